// Round 11
// baseline (525.529 us; speedup 1.0000x reference)
//
#include <hip/hip_runtime.h>
#include <hip/hip_bf16.h>
#include <stdint.h>

// Problem: B=4, S=1024, D=1024, H=16, HS=64. fp32 inputs/outputs, bf16 MFMA.
#define NEG_SENTINEL (-1e30f)

typedef short s16x8 __attribute__((ext_vector_type(8)));
typedef float f32x4 __attribute__((ext_vector_type(4)));

__device__ __forceinline__ ushort f2bf(float f) {  // RTNE
  union { float f; uint32_t u; } v; v.f = f;
  uint32_t u = v.u;
  u += 0x7fffu + ((u >> 16) & 1u);
  return (ushort)(u >> 16);
}
__device__ __forceinline__ ushort f2bf_rn(float f) {  // round-nearest (cheap)
  union { float f; uint32_t u; } v; v.f = f;
  return (ushort)((v.u + 0x8000u) >> 16);
}

// async global->LDS, 16 B per lane. LDS dest: wave-uniform base + lane*16.
__device__ __forceinline__ void async_ld16(ushort* lds, const ushort* g) {
  __builtin_amdgcn_global_load_lds(
      (const __attribute__((address_space(1))) uint32_t*)g,
      (__attribute__((address_space(3))) uint32_t*)lds, 16, 0, 0);
}

// ---------------------------------------------------------------------------
// Software grid barrier (all 512 blocks co-resident by construction:
// launch_bounds(256,2) + LDS 53.2KB -> exactly 2 blocks/CU, grid = 2*256).
// Agent-scope atomics + fences handle cross-XCD coherence (G16).
// Bounded spin: degrades instead of hanging if residency assumption breaks.
// ---------------------------------------------------------------------------
__device__ void grid_barrier(uint32_t* cnt, uint32_t target) {
  __syncthreads();
  if (threadIdx.x == 0) {
    __threadfence();  // release: write back this XCD's dirty L2
    __hip_atomic_fetch_add(cnt, 1u, __ATOMIC_ACQ_REL, __HIP_MEMORY_SCOPE_AGENT);
    uint32_t guard = 0;
    while (__hip_atomic_load(cnt, __ATOMIC_ACQUIRE,
                             __HIP_MEMORY_SCOPE_AGENT) < target) {
      __builtin_amdgcn_s_sleep(32);
      if (++guard > (1u << 21)) break;  // bail ~100ms-equiv, no hang
    }
    __threadfence();  // acquire: invalidate stale L1/L2
  }
  __syncthreads();
}

// ---------------------------------------------------------------------------
// Prep unit (one of 3072):
//   [0, 2048)    : data fp32 -> bf16 (8 elems/thread)
//   [2048, 2816) : Wq/Wk/Wv per-head transpose (48 heads x 16 row-tiles)
//   [2816, 3072) : Wo transpose (16x16 tiles)
// ---------------------------------------------------------------------------
__device__ void prep_unit(int blk, int tid, const float* __restrict__ data,
                          const float* __restrict__ Wq, const float* __restrict__ Wk,
                          const float* __restrict__ Wv, const float* __restrict__ Wo,
                          ushort* __restrict__ dataB, ushort* __restrict__ WTall,
                          ushort* __restrict__ WoT, ushort* tile) {
  if (blk < 2048) {
    long i = ((long)blk * 256 + tid) * 8;
    float4 a = *(const float4*)(data + i);
    float4 b = *(const float4*)(data + i + 4);
    union { ushort u[8]; uint4 v; } o;
    o.u[0] = f2bf(a.x); o.u[1] = f2bf(a.y); o.u[2] = f2bf(a.z); o.u[3] = f2bf(a.w);
    o.u[4] = f2bf(b.x); o.u[5] = f2bf(b.y); o.u[6] = f2bf(b.z); o.u[7] = f2bf(b.w);
    *(uint4*)(dataB + i) = o.v;
    return;
  }
  const float* src;
  ushort* dst;
  int srcCols, dstRowStride, it, jt;
  if (blk < 2816) {
    int t = blk - 2048;
    int z = t >> 4;
    it = t & 15;  jt = 0;
    int matsel = z >> 4;
    src = (matsel == 0 ? Wq : (matsel == 1 ? Wk : Wv)) + (long)(z & 15) * 65536;
    dst = WTall + (long)z * 65536;
    srcCols = 64; dstRowStride = 1024;
  } else {
    int t = blk - 2816;
    jt = t & 15; it = t >> 4;
    src = Wo; dst = WoT;
    srcCols = 1024; dstRowStride = 1024;
  }
#pragma unroll
  for (int p = 0; p < 4; ++p) {
    int chunk = tid + p * 256;
    int r = chunk >> 4, c0 = (chunk & 15) * 4;
    float4 f = *(const float4*)(src + (long)(it * 64 + r) * srcCols + jt * 64 + c0);
    union { ushort u[4]; uint2 v; } o;
    o.u[0] = f2bf(f.x); o.u[1] = f2bf(f.y); o.u[2] = f2bf(f.z); o.u[3] = f2bf(f.w);
    *(uint2*)&tile[r * 72 + c0] = o.v;
  }
  __syncthreads();
#pragma unroll
  for (int p = 0; p < 2; ++p) {
    int chunk = tid + p * 256;
    int r = chunk >> 3, c0 = (chunk & 7) * 8;
    union { ushort u[8]; uint4 v; } tmp;
#pragma unroll
    for (int k2 = 0; k2 < 8; ++k2) tmp.u[k2] = tile[(c0 + k2) * 72 + r];
    *(uint4*)(dst + (long)(jt * 64 + r) * dstRowStride + it * 64 + c0) = tmp.v;
  }
}

// ---------------------------------------------------------------------------
// m97-style GEMM core: C[128x128] += A[128xK] * BT[128 n][K], K=1024, BK=64.
// ---------------------------------------------------------------------------
__device__ __forceinline__ void gemm_core_128x128(
    const ushort* __restrict__ A, const ushort* __restrict__ BT,
    ushort* As, ushort* Bs, f32x4 acc[4][4]) {
  const int tid = threadIdx.x;
  const int lane = tid & 63, w = tid >> 6, quad = lane >> 4, l15 = lane & 15;
  const int wm = w >> 1, wn = w & 1;
  for (int k0 = 0; k0 < 1024; k0 += 64) {
#pragma unroll
    for (int p = 0; p < 4; ++p) {
      int c = tid + p * 256;
      int r = c >> 3, c8 = (c & 7) * 8;
      async_ld16(As + c * 8, A + (long)r * 1024 + k0 + c8);
      async_ld16(Bs + c * 8, BT + (long)r * 1024 + k0 + c8);
    }
    __syncthreads();
#pragma unroll
    for (int kk = 0; kk < 64; kk += 32) {
      s16x8 af[4], bfr[4];
#pragma unroll
      for (int mi = 0; mi < 4; ++mi)
        af[mi] = *(const s16x8*)&As[(wm * 64 + mi * 16 + l15) * 64 + kk + quad * 8];
#pragma unroll
      for (int ni = 0; ni < 4; ++ni)
        bfr[ni] = *(const s16x8*)&Bs[(wn * 64 + ni * 16 + l15) * 64 + kk + quad * 8];
#pragma unroll
      for (int mi = 0; mi < 4; ++mi)
#pragma unroll
        for (int ni = 0; ni < 4; ++ni)
          acc[mi][ni] = __builtin_amdgcn_mfma_f32_16x16x32_bf16(
              af[mi], bfr[ni], acc[mi][ni], 0, 0, 0);
    }
    __syncthreads();
  }
}

// ---------------------------------------------------------------------------
// One QKV tile (of 768): t -> m0=(t&31)*128, n0=(t>>5)*128.
// Q pre-scaled by 1/sqrt(D). V stored transposed -> VT [b][h][e][s].
// ---------------------------------------------------------------------------
__device__ void qkv_tile(int t, const ushort* __restrict__ dataB,
                         const ushort* __restrict__ WTall,
                         ushort* __restrict__ QKV, ushort* smem) {
  ushort* As = smem;
  ushort* Bs = smem + 8192;
  ushort* Ct = smem;                     // stride 136 (17408 elems)
  const int m0 = (t & 31) * 128;
  const int n0 = (t >> 5) * 128;
  f32x4 acc[4][4];
  const f32x4 z = {0.f, 0.f, 0.f, 0.f};
#pragma unroll
  for (int mi = 0; mi < 4; ++mi)
#pragma unroll
    for (int ni = 0; ni < 4; ++ni) acc[mi][ni] = z;
  gemm_core_128x128(dataB + (long)m0 * 1024, WTall + (long)n0 * 1024, As, Bs, acc);

  const int tid = threadIdx.x;
  const int lane = tid & 63, w = tid >> 6, quad = lane >> 4, l15 = lane & 15;
  const int wm = w >> 1, wn = w & 1;
  const int matsel = n0 >> 10;
  const int bI = m0 >> 10, s0 = m0 & 1023;

  if (matsel < 2) {
    const float sc = (matsel == 0) ? 0.03125f : 1.0f;
    ushort* base = QKV + (long)matsel * 4194304 + (long)bI * 1048576;
#pragma unroll
    for (int mi = 0; mi < 4; ++mi) {
#pragma unroll
      for (int ni = 0; ni < 4; ++ni) {
        int n = n0 + wn * 64 + ni * 16 + l15;
        int h = (n >> 6) & 15, e = n & 63;
        ushort* col = base + (long)h * 65536 + e;
#pragma unroll
        for (int i = 0; i < 4; ++i) {
          int s = s0 + wm * 64 + mi * 16 + quad * 4 + i;
          col[s * 64] = f2bf(acc[mi][ni][i] * sc);
        }
      }
    }
  } else {
#pragma unroll
    for (int mi = 0; mi < 4; ++mi)
#pragma unroll
      for (int ni = 0; ni < 4; ++ni)
#pragma unroll
        for (int i = 0; i < 4; ++i)
          Ct[(wn * 64 + ni * 16 + l15) * 136 + wm * 64 + mi * 16 + quad * 4 + i] =
              f2bf(acc[mi][ni][i]);
    __syncthreads();
    ushort* base = QKV + 8388608 + (long)bI * 1048576;
#pragma unroll
    for (int p = 0; p < 8; ++p) {
      int c = tid + p * 256;
      int r = c >> 4, m8 = (c & 15) * 8;
      int h = ((n0 + r) >> 6) & 15, e = (n0 + r) & 63;
      *(uint4*)(base + (long)h * 65536 + e * 1024 + s0 + m8) =
          *(const uint4*)&Ct[r * 136 + m8];
    }
  }
}

// ---------------------------------------------------------------------------
// One out_proj tile (of 256): t -> m0=(t&31)*128, n0=(t>>5)*128.
// ---------------------------------------------------------------------------
__device__ void out_tile(int t, const ushort* __restrict__ Ocat,
                         const ushort* __restrict__ WoT,
                         const float* __restrict__ bo, float* __restrict__ out,
                         ushort* smem) {
  ushort* As = smem;
  ushort* Bs = smem + 8192;
  const int m0 = (t & 31) * 128;
  const int n0 = (t >> 5) * 128;
  f32x4 acc[4][4];
  const f32x4 z = {0.f, 0.f, 0.f, 0.f};
#pragma unroll
  for (int mi = 0; mi < 4; ++mi)
#pragma unroll
    for (int ni = 0; ni < 4; ++ni) acc[mi][ni] = z;
  gemm_core_128x128(Ocat + (long)m0 * 1024, WoT + (long)n0 * 1024, As, Bs, acc);

  const int tid = threadIdx.x;
  const int lane = tid & 63, w = tid >> 6, quad = lane >> 4, l15 = lane & 15;
  const int wm = w >> 1, wn = w & 1;
#pragma unroll
  for (int mi = 0; mi < 4; ++mi) {
#pragma unroll
    for (int ni = 0; ni < 4; ++ni) {
#pragma unroll
      for (int i = 0; i < 4; ++i) {
        int m = m0 + wm * 64 + mi * 16 + quad * 4 + i;
        int n = n0 + wn * 64 + ni * 16 + l15;
        out[(long)m * 1024 + n] = acc[mi][ni][i] + bo[n];
      }
    }
  }
}

// ---------------------------------------------------------------------------
// Attention block (R9 balanced pairing): bh in [0,64), y in [0,8).
// Processes q-tiles (y, 15-y): exactly 9 K-iterations per block.
// smem carve: Ks [128][72] | Vs [64][136] | Ps 4x[16][136] = 53248 B.
// ---------------------------------------------------------------------------
__device__ void attn_block(int bh, int y, const ushort* __restrict__ QKV,
                           ushort* __restrict__ Ocat, ushort* smem) {
  ushort* Ks = smem;
  ushort* Vs = smem + 9216;
  ushort* Ps = smem + 17920;
  const int b = bh >> 4, h = bh & 15;
  const int tid = threadIdx.x;
  const int w = tid >> 6, lane = tid & 63, quad = lane >> 4, l15 = lane & 15;

  const ushort* Qp = QKV + (long)bh * 65536;
  const ushort* Kp = QKV + 4194304 + (long)bh * 65536;
  const ushort* VTp = QKV + 8388608 + (long)bh * 65536;
  ushort* Psw = Ps + w * (16 * 136);
  const f32x4 z = {0.f, 0.f, 0.f, 0.f};

#pragma unroll
  for (int phase = 0; phase < 2; ++phase) {
    const int qt = phase == 0 ? y : 15 - y;
    const int q0 = qt * 64;
    const int nj = (qt >> 1) + 1;

    const int qrow = q0 + w * 16 + l15;
    s16x8 qf0 = *(const s16x8*)(Qp + (long)qrow * 64 + quad * 8);
    s16x8 qf1 = *(const s16x8*)(Qp + (long)qrow * 64 + 32 + quad * 8);

    f32x4 oacc[4];
#pragma unroll
    for (int et = 0; et < 4; ++et) oacc[et] = z;
    float l_i[4] = {0.f, 0.f, 0.f, 0.f};

    for (int j = 0; j < nj; ++j) {
#pragma unroll
      for (int p = 0; p < 4; ++p) {
        int c = tid + p * 256;
        { int r = c >> 3, c8 = (c & 7) * 8;
          *(uint4*)&Ks[r * 72 + c8] =
              *(const uint4*)(Kp + (long)(j * 128 + r) * 64 + c8); }
        { int r = c >> 4, c8 = (c & 15) * 8;
          *(uint4*)&Vs[r * 136 + c8] =
              *(const uint4*)(VTp + (long)r * 1024 + j * 128 + c8); }
      }
      __syncthreads();

      f32x4 sacc[8];
#pragma unroll
      for (int nt = 0; nt < 8; ++nt) sacc[nt] = z;
#pragma unroll
      for (int kk = 0; kk < 64; kk += 32) {
        s16x8 a = kk ? qf1 : qf0;
#pragma unroll
        for (int nt = 0; nt < 8; ++nt) {
          s16x8 bfr = *(const s16x8*)&Ks[(nt * 16 + l15) * 72 + kk + quad * 8];
          sacc[nt] = __builtin_amdgcn_mfma_f32_16x16x32_bf16(a, bfr, sacc[nt], 0, 0, 0);
        }
      }

      if (j == nj - 1) {  // diagonal tile: causal mask
        const int srow = q0 + w * 16 + quad * 4;
#pragma unroll
        for (int nt = 0; nt < 8; ++nt) {
#pragma unroll
          for (int i = 0; i < 4; ++i) {
            int tg = j * 128 + nt * 16 + l15;
            if (tg > srow + i) sacc[nt][i] = NEG_SENTINEL;
          }
        }
      }

#pragma unroll
      for (int i = 0; i < 4; ++i) {
#pragma unroll
        for (int nt = 0; nt < 8; ++nt) {
          float p = __expf(sacc[nt][i]);
          Psw[(quad * 4 + i) * 136 + nt * 16 + l15] = f2bf_rn(p);
          l_i[i] += p;
        }
      }

#pragma unroll
      for (int kk = 0; kk < 128; kk += 32) {
        s16x8 pa = *(const s16x8*)&Psw[l15 * 136 + kk + quad * 8];
#pragma unroll
        for (int et = 0; et < 4; ++et) {
          s16x8 vb = *(const s16x8*)&Vs[(et * 16 + l15) * 136 + kk + quad * 8];
          oacc[et] = __builtin_amdgcn_mfma_f32_16x16x32_bf16(pa, vb, oacc[et], 0, 0, 0);
        }
      }
      __syncthreads();
    }

#pragma unroll
    for (int i = 0; i < 4; ++i) {
#pragma unroll
      for (int d = 1; d < 16; d <<= 1) l_i[i] += __shfl_xor(l_i[i], d, 64);
    }
    ushort* Ob = Ocat + ((long)(b * 1024 + q0 + w * 16) * 1024) + h * 64;
#pragma unroll
    for (int et = 0; et < 4; ++et) {
#pragma unroll
      for (int i = 0; i < 4; ++i) {
        float denom = l_i[i];
        float v = oacc[et][i] / (denom > 0.f ? denom : 1.0f);
        Ob[(long)(quad * 4 + i) * 1024 + et * 16 + l15] = f2bf_rn(v);
      }
    }
  }
}

// ---------------------------------------------------------------------------
// Mega-kernel, plain launch + software grid barriers.
// Workspace (ushort elems):
//   [0, 12M)    QKV (Q pre-scaled | K | VT)
//   [12M, 16M)  dataB (phases A,B) -> Ocat (phases C,D)  [aliased]
//   [16M, +128) sync counters (NEVER phase-written; memset each launch)
//   [20M, 23M)  WTall | [23M, 24M) WoT
// ---------------------------------------------------------------------------
__global__ __launch_bounds__(256, 2) void mega_kernel(
    const float* __restrict__ data, const float* __restrict__ Wq,
    const float* __restrict__ Wk, const float* __restrict__ Wv,
    const float* __restrict__ Wo, const float* __restrict__ bo,
    float* __restrict__ out, ushort* __restrict__ ws) {
  __shared__ __align__(16) ushort smem[26624];   // 53248 B arena
  __shared__ int curT;
  const int bid = blockIdx.x;
  const int tid = threadIdx.x;

  ushort* QKV = ws;
  ushort* dataB = ws + 12582912;
  ushort* Ocat = ws + 12582912;          // alias: dataB dead after phase B
  uint32_t* sync = (uint32_t*)(ws + 16777216);
  ushort* WTall = ws + 20971520;
  ushort* WoT = ws + 20971520 + 3145728;

  // ---- Phase A: prep (3072 units, 6 per block) ----
#pragma unroll
  for (int i = 0; i < 6; ++i) {
    prep_unit(bid + 512 * i, tid, data, Wq, Wk, Wv, Wo, dataB, WTall, WoT, smem);
    __syncthreads();
  }
  grid_barrier(&sync[0], 512);

  // ---- Phase B: QKV projection (768 tiles via work queue) ----
  for (;;) {
    if (tid == 0)
      curT = (int)__hip_atomic_fetch_add(&sync[24], 1u, __ATOMIC_RELAXED,
                                         __HIP_MEMORY_SCOPE_AGENT);
    __syncthreads();
    int t = curT;
    if (t >= 768) break;
    qkv_tile(t, dataB, WTall, QKV, smem);
    __syncthreads();
  }
  grid_barrier(&sync[8], 512);

  // ---- Phase C: attention (512 blocks = 64 bh x 8 balanced pair-tiles) ----
  attn_block(bid >> 3, bid & 7, QKV, Ocat, smem);
  grid_barrier(&sync[16], 512);

  // ---- Phase D: output projection (256 tiles via work queue) ----
  for (;;) {
    if (tid == 0)
      curT = (int)__hip_atomic_fetch_add(&sync[28], 1u, __ATOMIC_RELAXED,
                                         __HIP_MEMORY_SCOPE_AGENT);
    __syncthreads();
    int t = curT;
    if (t >= 256) break;
    out_tile(t, Ocat, WoT, bo, out, smem);
    __syncthreads();
  }
}

extern "C" void kernel_launch(void* const* d_in, const int* in_sizes, int n_in,
                              void* d_out, int out_size, void* d_ws, size_t ws_size,
                              hipStream_t stream) {
  const float* data = (const float*)d_in[0];
  const float* Wq = (const float*)d_in[1];
  const float* Wk = (const float*)d_in[2];
  const float* Wv = (const float*)d_in[3];
  const float* Wo = (const float*)d_in[4];
  const float* bo = (const float*)d_in[5];
  float* out = (float*)d_out;
  ushort* wsp = (ushort*)d_ws;

  // Zero the barrier/queue counters (graph-capturable async memset).
  hipMemsetAsync((char*)d_ws + 33554432, 0, 128, stream);
  mega_kernel<<<dim3(512), dim3(256), 0, stream>>>(data, Wq, Wk, Wv, Wo, bo,
                                                   out, wsp);
}

// Round 12
// 365.883 us; speedup vs baseline: 1.4363x; 1.4363x over previous
//
#include <hip/hip_runtime.h>
#include <hip/hip_bf16.h>
#include <stdint.h>

// Problem: B=4, S=1024, D=1024, H=16, HS=64. fp32 inputs/outputs, bf16 MFMA.
#define NEG_SENTINEL (-1e30f)

typedef short s16x8 __attribute__((ext_vector_type(8)));
typedef float f32x4 __attribute__((ext_vector_type(4)));

__device__ __forceinline__ ushort f2bf(float f) {  // RTNE
  union { float f; uint32_t u; } v; v.f = f;
  uint32_t u = v.u;
  u += 0x7fffu + ((u >> 16) & 1u);
  return (ushort)(u >> 16);
}
__device__ __forceinline__ ushort f2bf_rn(float f) {  // round-nearest (cheap)
  union { float f; uint32_t u; } v; v.f = f;
  return (ushort)((v.u + 0x8000u) >> 16);
}

// async global->LDS, 16 B per lane. LDS dest: wave-uniform base + lane*16.
__device__ __forceinline__ void async_ld16(ushort* lds, const ushort* g) {
  __builtin_amdgcn_global_load_lds(
      (const __attribute__((address_space(1))) uint32_t*)g,
      (__attribute__((address_space(3))) uint32_t*)lds, 16, 0, 0);
}

// ---------------------------------------------------------------------------
// Software grid barrier. All 512 blocks co-resident (launch_bounds(256,2),
// LDS 53.2KB -> 2 blocks/CU x 256 CUs). KEY FIX vs R11: spin with RELAXED
// loads (no per-iteration cache invalidate); ONE acquire fence after exit.
// R11's ACQUIRE-spin emitted buffer_inv every iteration -> 512 blocks
// continuously invalidated L2 while others computed -> 3x HBM refetch.
// ---------------------------------------------------------------------------
__device__ void grid_barrier(uint32_t* cnt, uint32_t target) {
  __syncthreads();
  if (threadIdx.x == 0) {
    __threadfence();  // release: write back dirty L2 before signaling
    __hip_atomic_fetch_add(cnt, 1u, __ATOMIC_RELAXED, __HIP_MEMORY_SCOPE_AGENT);
    uint32_t guard = 0;
    while (__hip_atomic_load(cnt, __ATOMIC_RELAXED,
                             __HIP_MEMORY_SCOPE_AGENT) < target) {
      __builtin_amdgcn_s_sleep(8);
      if (++guard > (1u << 20)) break;  // bounded: degrade, never hang
    }
    __threadfence();  // acquire ONCE: invalidate stale L1/L2 after release
  }
  __syncthreads();
}

// ---------------------------------------------------------------------------
// Prep unit (one of 3072):
//   [0, 2048)    : data fp32 -> bf16 (8 elems/thread)
//   [2048, 2816) : Wq/Wk/Wv per-head transpose (48 heads x 16 row-tiles)
//   [2816, 3072) : Wo transpose (16x16 tiles)
// ---------------------------------------------------------------------------
__device__ void prep_unit(int blk, int tid, const float* __restrict__ data,
                          const float* __restrict__ Wq, const float* __restrict__ Wk,
                          const float* __restrict__ Wv, const float* __restrict__ Wo,
                          ushort* __restrict__ dataB, ushort* __restrict__ WTall,
                          ushort* __restrict__ WoT, ushort* tile) {
  if (blk < 2048) {
    long i = ((long)blk * 256 + tid) * 8;
    float4 a = *(const float4*)(data + i);
    float4 b = *(const float4*)(data + i + 4);
    union { ushort u[8]; uint4 v; } o;
    o.u[0] = f2bf(a.x); o.u[1] = f2bf(a.y); o.u[2] = f2bf(a.z); o.u[3] = f2bf(a.w);
    o.u[4] = f2bf(b.x); o.u[5] = f2bf(b.y); o.u[6] = f2bf(b.z); o.u[7] = f2bf(b.w);
    *(uint4*)(dataB + i) = o.v;
    return;
  }
  const float* src;
  ushort* dst;
  int srcCols, dstRowStride, it, jt;
  if (blk < 2816) {
    int t = blk - 2048;
    int z = t >> 4;
    it = t & 15;  jt = 0;
    int matsel = z >> 4;
    src = (matsel == 0 ? Wq : (matsel == 1 ? Wk : Wv)) + (long)(z & 15) * 65536;
    dst = WTall + (long)z * 65536;
    srcCols = 64; dstRowStride = 1024;
  } else {
    int t = blk - 2816;
    jt = t & 15; it = t >> 4;
    src = Wo; dst = WoT;
    srcCols = 1024; dstRowStride = 1024;
  }
#pragma unroll
  for (int p = 0; p < 4; ++p) {
    int chunk = tid + p * 256;
    int r = chunk >> 4, c0 = (chunk & 15) * 4;
    float4 f = *(const float4*)(src + (long)(it * 64 + r) * srcCols + jt * 64 + c0);
    union { ushort u[4]; uint2 v; } o;
    o.u[0] = f2bf(f.x); o.u[1] = f2bf(f.y); o.u[2] = f2bf(f.z); o.u[3] = f2bf(f.w);
    *(uint2*)&tile[r * 72 + c0] = o.v;
  }
  __syncthreads();
#pragma unroll
  for (int p = 0; p < 2; ++p) {
    int chunk = tid + p * 256;
    int r = chunk >> 3, c0 = (chunk & 7) * 8;
    union { ushort u[8]; uint4 v; } tmp;
#pragma unroll
    for (int k2 = 0; k2 < 8; ++k2) tmp.u[k2] = tile[(c0 + k2) * 72 + r];
    *(uint4*)(dst + (long)(jt * 64 + r) * dstRowStride + it * 64 + c0) = tmp.v;
  }
}

// ---------------------------------------------------------------------------
// m97-style GEMM core: C[128x128] += A[128xK] * BT[128 n][K], K=1024, BK=64.
// ---------------------------------------------------------------------------
__device__ __forceinline__ void gemm_core_128x128(
    const ushort* __restrict__ A, const ushort* __restrict__ BT,
    ushort* As, ushort* Bs, f32x4 acc[4][4]) {
  const int tid = threadIdx.x;
  const int lane = tid & 63, w = tid >> 6, quad = lane >> 4, l15 = lane & 15;
  const int wm = w >> 1, wn = w & 1;
  for (int k0 = 0; k0 < 1024; k0 += 64) {
#pragma unroll
    for (int p = 0; p < 4; ++p) {
      int c = tid + p * 256;
      int r = c >> 3, c8 = (c & 7) * 8;
      async_ld16(As + c * 8, A + (long)r * 1024 + k0 + c8);
      async_ld16(Bs + c * 8, BT + (long)r * 1024 + k0 + c8);
    }
    __syncthreads();
#pragma unroll
    for (int kk = 0; kk < 64; kk += 32) {
      s16x8 af[4], bfr[4];
#pragma unroll
      for (int mi = 0; mi < 4; ++mi)
        af[mi] = *(const s16x8*)&As[(wm * 64 + mi * 16 + l15) * 64 + kk + quad * 8];
#pragma unroll
      for (int ni = 0; ni < 4; ++ni)
        bfr[ni] = *(const s16x8*)&Bs[(wn * 64 + ni * 16 + l15) * 64 + kk + quad * 8];
#pragma unroll
      for (int mi = 0; mi < 4; ++mi)
#pragma unroll
        for (int ni = 0; ni < 4; ++ni)
          acc[mi][ni] = __builtin_amdgcn_mfma_f32_16x16x32_bf16(
              af[mi], bfr[ni], acc[mi][ni], 0, 0, 0);
    }
    __syncthreads();
  }
}

// ---------------------------------------------------------------------------
// One QKV tile (of 768): t -> m0=(t&31)*128, n0=(t>>5)*128.
// Q pre-scaled by 1/sqrt(D). V stored transposed -> VT [b][h][e][s].
// ---------------------------------------------------------------------------
__device__ void qkv_tile(int t, const ushort* __restrict__ dataB,
                         const ushort* __restrict__ WTall,
                         ushort* __restrict__ QKV, ushort* smem) {
  ushort* As = smem;
  ushort* Bs = smem + 8192;
  ushort* Ct = smem;                     // stride 136 (17408 elems)
  const int m0 = (t & 31) * 128;
  const int n0 = (t >> 5) * 128;
  f32x4 acc[4][4];
  const f32x4 z = {0.f, 0.f, 0.f, 0.f};
#pragma unroll
  for (int mi = 0; mi < 4; ++mi)
#pragma unroll
    for (int ni = 0; ni < 4; ++ni) acc[mi][ni] = z;
  gemm_core_128x128(dataB + (long)m0 * 1024, WTall + (long)n0 * 1024, As, Bs, acc);

  const int tid = threadIdx.x;
  const int lane = tid & 63, w = tid >> 6, quad = lane >> 4, l15 = lane & 15;
  const int wm = w >> 1, wn = w & 1;
  const int matsel = n0 >> 10;
  const int bI = m0 >> 10, s0 = m0 & 1023;

  if (matsel < 2) {
    const float sc = (matsel == 0) ? 0.03125f : 1.0f;
    ushort* base = QKV + (long)matsel * 4194304 + (long)bI * 1048576;
#pragma unroll
    for (int mi = 0; mi < 4; ++mi) {
#pragma unroll
      for (int ni = 0; ni < 4; ++ni) {
        int n = n0 + wn * 64 + ni * 16 + l15;
        int h = (n >> 6) & 15, e = n & 63;
        ushort* col = base + (long)h * 65536 + e;
#pragma unroll
        for (int i = 0; i < 4; ++i) {
          int s = s0 + wm * 64 + mi * 16 + quad * 4 + i;
          col[s * 64] = f2bf(acc[mi][ni][i] * sc);
        }
      }
    }
  } else {
#pragma unroll
    for (int mi = 0; mi < 4; ++mi)
#pragma unroll
      for (int ni = 0; ni < 4; ++ni)
#pragma unroll
        for (int i = 0; i < 4; ++i)
          Ct[(wn * 64 + ni * 16 + l15) * 136 + wm * 64 + mi * 16 + quad * 4 + i] =
              f2bf(acc[mi][ni][i]);
    __syncthreads();
    ushort* base = QKV + 8388608 + (long)bI * 1048576;
#pragma unroll
    for (int p = 0; p < 8; ++p) {
      int c = tid + p * 256;
      int r = c >> 4, m8 = (c & 15) * 8;
      int h = ((n0 + r) >> 6) & 15, e = (n0 + r) & 63;
      *(uint4*)(base + (long)h * 65536 + e * 1024 + s0 + m8) =
          *(const uint4*)&Ct[r * 136 + m8];
    }
  }
}

// ---------------------------------------------------------------------------
// One out_proj tile (of 256): t -> m0=(t&31)*128, n0=(t>>5)*128.
// ---------------------------------------------------------------------------
__device__ void out_tile(int t, const ushort* __restrict__ Ocat,
                         const ushort* __restrict__ WoT,
                         const float* __restrict__ bo, float* __restrict__ out,
                         ushort* smem) {
  ushort* As = smem;
  ushort* Bs = smem + 8192;
  const int m0 = (t & 31) * 128;
  const int n0 = (t >> 5) * 128;
  f32x4 acc[4][4];
  const f32x4 z = {0.f, 0.f, 0.f, 0.f};
#pragma unroll
  for (int mi = 0; mi < 4; ++mi)
#pragma unroll
    for (int ni = 0; ni < 4; ++ni) acc[mi][ni] = z;
  gemm_core_128x128(Ocat + (long)m0 * 1024, WoT + (long)n0 * 1024, As, Bs, acc);

  const int tid = threadIdx.x;
  const int lane = tid & 63, w = tid >> 6, quad = lane >> 4, l15 = lane & 15;
  const int wm = w >> 1, wn = w & 1;
#pragma unroll
  for (int mi = 0; mi < 4; ++mi) {
#pragma unroll
    for (int ni = 0; ni < 4; ++ni) {
#pragma unroll
      for (int i = 0; i < 4; ++i) {
        int m = m0 + wm * 64 + mi * 16 + quad * 4 + i;
        int n = n0 + wn * 64 + ni * 16 + l15;
        out[(long)m * 1024 + n] = acc[mi][ni][i] + bo[n];
      }
    }
  }
}

// ---------------------------------------------------------------------------
// Attention block (balanced pairing): bh in [0,64), y in [0,8).
// Processes q-tiles (y, 15-y): exactly 9 K-iterations per block.
// smem carve: Ks [128][72] | Vs [64][136] | Ps 4x[16][136] = 53248 B.
// ---------------------------------------------------------------------------
__device__ void attn_block(int bh, int y, const ushort* __restrict__ QKV,
                           ushort* __restrict__ Ocat, ushort* smem) {
  ushort* Ks = smem;
  ushort* Vs = smem + 9216;
  ushort* Ps = smem + 17920;
  const int b = bh >> 4, h = bh & 15;
  const int tid = threadIdx.x;
  const int w = tid >> 6, lane = tid & 63, quad = lane >> 4, l15 = lane & 15;

  const ushort* Qp = QKV + (long)bh * 65536;
  const ushort* Kp = QKV + 4194304 + (long)bh * 65536;
  const ushort* VTp = QKV + 8388608 + (long)bh * 65536;
  ushort* Psw = Ps + w * (16 * 136);
  const f32x4 z = {0.f, 0.f, 0.f, 0.f};

#pragma unroll
  for (int phase = 0; phase < 2; ++phase) {
    const int qt = phase == 0 ? y : 15 - y;
    const int q0 = qt * 64;
    const int nj = (qt >> 1) + 1;

    const int qrow = q0 + w * 16 + l15;
    s16x8 qf0 = *(const s16x8*)(Qp + (long)qrow * 64 + quad * 8);
    s16x8 qf1 = *(const s16x8*)(Qp + (long)qrow * 64 + 32 + quad * 8);

    f32x4 oacc[4];
#pragma unroll
    for (int et = 0; et < 4; ++et) oacc[et] = z;
    float l_i[4] = {0.f, 0.f, 0.f, 0.f};

    for (int j = 0; j < nj; ++j) {
#pragma unroll
      for (int p = 0; p < 4; ++p) {
        int c = tid + p * 256;
        { int r = c >> 3, c8 = (c & 7) * 8;
          *(uint4*)&Ks[r * 72 + c8] =
              *(const uint4*)(Kp + (long)(j * 128 + r) * 64 + c8); }
        { int r = c >> 4, c8 = (c & 15) * 8;
          *(uint4*)&Vs[r * 136 + c8] =
              *(const uint4*)(VTp + (long)r * 1024 + j * 128 + c8); }
      }
      __syncthreads();

      f32x4 sacc[8];
#pragma unroll
      for (int nt = 0; nt < 8; ++nt) sacc[nt] = z;
#pragma unroll
      for (int kk = 0; kk < 64; kk += 32) {
        s16x8 a = kk ? qf1 : qf0;
#pragma unroll
        for (int nt = 0; nt < 8; ++nt) {
          s16x8 bfr = *(const s16x8*)&Ks[(nt * 16 + l15) * 72 + kk + quad * 8];
          sacc[nt] = __builtin_amdgcn_mfma_f32_16x16x32_bf16(a, bfr, sacc[nt], 0, 0, 0);
        }
      }

      if (j == nj - 1) {  // diagonal tile: causal mask
        const int srow = q0 + w * 16 + quad * 4;
#pragma unroll
        for (int nt = 0; nt < 8; ++nt) {
#pragma unroll
          for (int i = 0; i < 4; ++i) {
            int tg = j * 128 + nt * 16 + l15;
            if (tg > srow + i) sacc[nt][i] = NEG_SENTINEL;
          }
        }
      }

#pragma unroll
      for (int i = 0; i < 4; ++i) {
#pragma unroll
        for (int nt = 0; nt < 8; ++nt) {
          float p = __expf(sacc[nt][i]);
          Psw[(quad * 4 + i) * 136 + nt * 16 + l15] = f2bf_rn(p);
          l_i[i] += p;
        }
      }

#pragma unroll
      for (int kk = 0; kk < 128; kk += 32) {
        s16x8 pa = *(const s16x8*)&Psw[l15 * 136 + kk + quad * 8];
#pragma unroll
        for (int et = 0; et < 4; ++et) {
          s16x8 vb = *(const s16x8*)&Vs[(et * 16 + l15) * 136 + kk + quad * 8];
          oacc[et] = __builtin_amdgcn_mfma_f32_16x16x32_bf16(pa, vb, oacc[et], 0, 0, 0);
        }
      }
      __syncthreads();
    }

#pragma unroll
    for (int i = 0; i < 4; ++i) {
#pragma unroll
      for (int d = 1; d < 16; d <<= 1) l_i[i] += __shfl_xor(l_i[i], d, 64);
    }
    ushort* Ob = Ocat + ((long)(b * 1024 + q0 + w * 16) * 1024) + h * 64;
#pragma unroll
    for (int et = 0; et < 4; ++et) {
#pragma unroll
      for (int i = 0; i < 4; ++i) {
        float denom = l_i[i];
        float v = oacc[et][i] / (denom > 0.f ? denom : 1.0f);
        Ob[(long)(quad * 4 + i) * 1024 + et * 16 + l15] = f2bf_rn(v);
      }
    }
  }
}

// ---------------------------------------------------------------------------
// Mega-kernel, plain launch + software grid barriers (relaxed-spin).
// Workspace (ushort elems):
//   [0, 12M)    QKV (Q pre-scaled | K | VT)
//   [12M, 16M)  dataB (phases A,B) -> Ocat (phases C,D)  [aliased]
//   [16M, +256B) sync counters (barriers at 0/16/32, queues at 48/56;
//                64B-separated lines; memset each launch)
//   [20M, 23M)  WTall | [23M, 24M) WoT
// ---------------------------------------------------------------------------
__global__ __launch_bounds__(256, 2) void mega_kernel(
    const float* __restrict__ data, const float* __restrict__ Wq,
    const float* __restrict__ Wk, const float* __restrict__ Wv,
    const float* __restrict__ Wo, const float* __restrict__ bo,
    float* __restrict__ out, ushort* __restrict__ ws) {
  __shared__ __align__(16) ushort smem[26624];   // 53248 B arena
  __shared__ int curT;
  const int bid = blockIdx.x;
  const int tid = threadIdx.x;

  ushort* QKV = ws;
  ushort* dataB = ws + 12582912;
  ushort* Ocat = ws + 12582912;          // alias: dataB dead after phase B
  uint32_t* sync = (uint32_t*)(ws + 16777216);
  ushort* WTall = ws + 20971520;
  ushort* WoT = ws + 20971520 + 3145728;

  // ---- Phase A: prep (3072 units, 6 per block) ----
#pragma unroll
  for (int i = 0; i < 6; ++i) {
    prep_unit(bid + 512 * i, tid, data, Wq, Wk, Wv, Wo, dataB, WTall, WoT, smem);
    __syncthreads();
  }
  grid_barrier(&sync[0], 512);

  // ---- Phase B: QKV projection (768 tiles via work queue) ----
  for (;;) {
    if (tid == 0)
      curT = (int)__hip_atomic_fetch_add(&sync[48], 1u, __ATOMIC_RELAXED,
                                         __HIP_MEMORY_SCOPE_AGENT);
    __syncthreads();
    int t = curT;
    if (t >= 768) break;
    qkv_tile(t, dataB, WTall, QKV, smem);
    __syncthreads();
  }
  grid_barrier(&sync[16], 512);

  // ---- Phase C: attention (512 blocks = 64 bh x 8 balanced pair-tiles) ----
  attn_block(bid >> 3, bid & 7, QKV, Ocat, smem);
  grid_barrier(&sync[32], 512);

  // ---- Phase D: output projection (256 tiles via work queue) ----
  for (;;) {
    if (tid == 0)
      curT = (int)__hip_atomic_fetch_add(&sync[56], 1u, __ATOMIC_RELAXED,
                                         __HIP_MEMORY_SCOPE_AGENT);
    __syncthreads();
    int t = curT;
    if (t >= 256) break;
    out_tile(t, Ocat, WoT, bo, out, smem);
    __syncthreads();
  }
}

extern "C" void kernel_launch(void* const* d_in, const int* in_sizes, int n_in,
                              void* d_out, int out_size, void* d_ws, size_t ws_size,
                              hipStream_t stream) {
  const float* data = (const float*)d_in[0];
  const float* Wq = (const float*)d_in[1];
  const float* Wk = (const float*)d_in[2];
  const float* Wv = (const float*)d_in[3];
  const float* Wo = (const float*)d_in[4];
  const float* bo = (const float*)d_in[5];
  float* out = (float*)d_out;
  ushort* wsp = (ushort*)d_ws;

  // Zero the barrier/queue counters (graph-capturable async memset).
  hipMemsetAsync((char*)d_ws + 33554432, 0, 256, stream);
  mega_kernel<<<dim3(512), dim3(256), 0, stream>>>(data, Wq, Wk, Wv, Wo, bo,
                                                   out, wsp);
}